// Round 8
// baseline (211.514 us; speedup 1.0000x reference)
//
#include <hip/hip_runtime.h>
#include <math.h>

#define IC     2401
#define BSZ    256
#define OCC    128     // OC*CS
#define XROW   19208   // x row length (floats) = IC*8
#define KP     19264   // padded K (=301*64), pad zeroed
#define KTILES 301
#define NI     64      // k-slices for sv_kernel (grid.y)
#define NBLK_S 256     // sv grid = 4 x 64

typedef __attribute__((ext_vector_type(8))) short short8;
typedef __attribute__((ext_vector_type(4))) float f32x4;

__device__ __forceinline__ unsigned short f2bf(float f) {
    union { float f; unsigned u; } v; v.f = f;
    const unsigned r = v.u + 0x7FFF + ((v.u >> 16) & 1);   // RNE
    return (unsigned short)(r >> 16);
}
__device__ __forceinline__ float bf2f(unsigned short h) {
    union { unsigned u; float f; } v; v.u = ((unsigned)h) << 16;
    return v.f;
}

// ---------------- prep: xT[k][b], xB[b][k], Wbf/cwt0 [oc][k] (bf16); zero sp+counters
__global__ __launch_bounds__(256)
void prep_kernel(const float* __restrict__ x, const float* __restrict__ W,
                 unsigned short* __restrict__ xT, unsigned short* __restrict__ xB,
                 unsigned short* __restrict__ Wbf, unsigned short* __restrict__ cwt,
                 float* __restrict__ sp, unsigned int* __restrict__ counters)
{
    const int tid = threadIdx.x;
    if (blockIdx.x < 32)    // zero sp: 32768 floats = 8192 float4
        ((float4*)sp)[blockIdx.x * 256 + tid] = make_float4(0.f, 0.f, 0.f, 0.f);
    if (blockIdx.x == 32 && tid < 3) counters[tid] = 0u;

    if (blockIdx.x < 1204) {
        __shared__ float Ts[64 * 65];
        const int bg = blockIdx.x & 3;       // b-group of 64
        const int kt = blockIdx.x >> 2;      // k-tile 0..300
#pragma unroll
        for (int r = 0; r < 4; ++r) {
            const int flat = r * 256 + tid;  // 1024 float4s
            const int b = flat >> 4, cq = flat & 15;
            const int col = kt * 64 + cq * 4;
            float4 v = make_float4(0.f, 0.f, 0.f, 0.f);
            if (col < XROW) v = *(const float4*)(x + (size_t)(bg * 64 + b) * XROW + col);
            *(float4*)&Ts[b * 65 + cq * 4] = v;
        }
        __syncthreads();
        // xT[k][b]
#pragma unroll
        for (int r = 0; r < 2; ++r) {
            const int flat = r * 256 + tid;
            const int rl = flat >> 3, bq = flat & 7;
            union { short8 v; unsigned short h[8]; } o;
#pragma unroll
            for (int j = 0; j < 8; ++j) o.h[j] = f2bf(Ts[(bq * 8 + j) * 65 + rl]);
            *(short8*)(xT + (size_t)(kt * 64 + rl) * 256 + bg * 64 + bq * 8) = o.v;
        }
        // xB[b][k]
#pragma unroll
        for (int r = 0; r < 2; ++r) {
            const int flat = r * 256 + tid;
            const int b = flat >> 3, g = flat & 7;
            union { short8 v; unsigned short h[8]; } o;
#pragma unroll
            for (int j = 0; j < 8; ++j) o.h[j] = f2bf(Ts[b * 65 + g * 8 + j]);
            *(short8*)(xB + (size_t)(bg * 64 + b) * KP + (size_t)kt * 64 + g * 8) = o.v;
        }
    } else {
        __shared__ float Ws[8 * 1032];
        const int i0 = (blockIdx.x - 1204) * 8;
#pragma unroll
        for (int r = 0; r < 8; ++r) {
            const int flat = r * 256 + tid;
            const int g = flat >> 8, rem = flat & 255;
            int gi = i0 + g; if (gi > 2400) gi = 2400;
            *(float4*)&Ws[g * 1032 + rem * 4] = *(const float4*)(W + (size_t)gi * 1024 + rem * 4);
        }
        __syncthreads();
#pragma unroll
        for (int r = 0; r < 4; ++r) {
            const int flat = r * 256 + tid;
            const int oc = flat >> 3, g = flat & 7;
            const int gi = i0 + g;
            union { short8 v; unsigned short h[8]; } w, c;
            if (gi <= 2400) {
                const float* wp = &Ws[g * 1032 + oc * 8];
#pragma unroll
                for (int j = 0; j < 8; ++j) { w.h[j] = f2bf(wp[j]); c.h[j] = f2bf(0.125f * wp[j]); }
            } else {
#pragma unroll
                for (int j = 0; j < 8; ++j) { w.h[j] = 0; c.h[j] = 0; }
            }
            *(short8*)(Wbf + (size_t)oc * KP + (size_t)gi * 8) = w.v;
            *(short8*)(cwt + (size_t)oc * KP + (size_t)gi * 8) = c.v;
        }
    }
}

// ---------------- sv: S (MFMA split-K, atomic accumulate into sp[256][128]) then
// last-arriving block squashes sp -> vT bf16 (and re-zeros sp) or -> out fp32.
__global__ __launch_bounds__(256, 2)
void sv_kernel(const unsigned short* __restrict__ xB, const unsigned short* __restrict__ cwt,
               float* __restrict__ sp, unsigned int* __restrict__ counter,
               unsigned short* __restrict__ vT, float* __restrict__ out, int final_it)
{
    __shared__ __align__(16) unsigned short Xs[64 * 64];    // 8 KB
    __shared__ __align__(16) unsigned short Bs[128 * 64];   // 16 KB
    __shared__ int is_last;
    const int tid = threadIdx.x;
    const int bg  = blockIdx.x, iy = blockIdx.y;
    const int b0  = bg * 64;
    const int ln  = tid & 63;
    const int mr  = ln & 15, qd = ln >> 4;
    const int mh  = (tid >> 6) & 1;        // m-half (32 b-rows)
    const int nh  = tid >> 7;              // n-half (64 oc)

    f32x4 acc[2][4];
#pragma unroll
    for (int a = 0; a < 2; ++a)
#pragma unroll
        for (int b = 0; b < 4; ++b) acc[a][b] = (f32x4){0.f, 0.f, 0.f, 0.f};

#pragma unroll 1
    for (int kt = iy; kt < KTILES; kt += NI) {
        __syncthreads();
#pragma unroll
        for (int r = 0; r < 2; ++r) {        // Xs <- xB (pure bf16 copy)
            const int flat = r * 256 + tid;
            const int b = flat >> 3, col = flat & 7;
            const short8 v = *(const short8*)(xB + (size_t)(b0 + b) * KP + (size_t)(kt * 8 + col) * 8);
            *(short8*)&Xs[b * 64 + ((col ^ (b & 7)) * 8)] = v;
        }
#pragma unroll
        for (int r = 0; r < 4; ++r) {        // Bs <- cwt
            const int flat = r * 256 + tid;
            const int oc = flat >> 3, col = flat & 7;
            const short8 w = *(const short8*)(cwt + (size_t)oc * KP + (size_t)(kt * 8 + col) * 8);
            *(short8*)&Bs[oc * 64 + ((col ^ (oc & 7)) * 8)] = w;
        }
        __syncthreads();
#pragma unroll
        for (int kk = 0; kk < 2; ++kk) {
            const int csw = ((kk * 4 + qd) ^ (mr & 7)) * 8;
            const short8 a0 = *(const short8*)&Xs[(mh * 32 + mr) * 64 + csw];
            const short8 a1 = *(const short8*)&Xs[(mh * 32 + 16 + mr) * 64 + csw];
#pragma unroll
            for (int nt = 0; nt < 4; ++nt) {
                const short8 b = *(const short8*)&Bs[(nh * 64 + nt * 16 + mr) * 64 + csw];
                acc[0][nt] = __builtin_amdgcn_mfma_f32_16x16x32_bf16(a0, b, acc[0][nt], 0, 0, 0);
                acc[1][nt] = __builtin_amdgcn_mfma_f32_16x16x32_bf16(a1, b, acc[1][nt], 0, 0, 0);
            }
        }
    }

#pragma unroll
    for (int mt = 0; mt < 2; ++mt)
#pragma unroll
        for (int nt = 0; nt < 4; ++nt)
#pragma unroll
            for (int r = 0; r < 4; ++r)
                unsafeAtomicAdd(&sp[(size_t)(b0 + mh * 32 + mt * 16 + qd * 4 + r) * OCC
                                    + nh * 64 + nt * 16 + mr], acc[mt][nt][r]);

    // ---- arrival: release (per-wave drain + visibility), then counter bump
    __threadfence();                      // all threads: waits own wave's atomics
    __syncthreads();                      // all waves arrived => all atomics complete
    if (tid == 0) {
        const unsigned old = atomicAdd(counter, 1u);
        is_last = (old == (unsigned)(NBLK_S - 1));
    }
    __syncthreads();
    if (!is_last) return;
    __threadfence();                      // acquire: invalidate L1 + cross-XCD L2 lines

    // ---- V: 2048 rows (= b*8+o), 8 rows/thread, coalesced row-per-lane reads
#pragma unroll 1
    for (int rr = 0; rr < 8; ++rr) {
        const int row = rr * 256 + tid;
        const float4* pr = (const float4*)(sp + (size_t)row * 16);
        const float4 t0 = pr[0], t1 = pr[1], t2 = pr[2], t3 = pr[3];
        float ms = 0.0f;
        ms = fmaf(t0.x, t0.x, ms); ms = fmaf(t0.y, t0.y, ms);
        ms = fmaf(t0.z, t0.z, ms); ms = fmaf(t0.w, t0.w, ms);
        ms = fmaf(t1.x, t1.x, ms); ms = fmaf(t1.y, t1.y, ms);
        ms = fmaf(t1.z, t1.z, ms); ms = fmaf(t1.w, t1.w, ms);
        ms = fmaf(t2.x, t2.x, ms); ms = fmaf(t2.y, t2.y, ms);
        ms = fmaf(t2.z, t2.z, ms); ms = fmaf(t2.w, t2.w, ms);
        ms = fmaf(t3.x, t3.x, ms); ms = fmaf(t3.y, t3.y, ms);
        ms = fmaf(t3.z, t3.z, ms); ms = fmaf(t3.w, t3.w, ms);
        const float sc = sqrtf(ms) / (1.0f + ms);   // == mag_sq/(1+mag_sq)/mag
        if (final_it) {
            float4* o4 = (float4*)(out + (size_t)row * 16);
            o4[0] = make_float4(t0.x * sc, t0.y * sc, t0.z * sc, t0.w * sc);
            o4[1] = make_float4(t1.x * sc, t1.y * sc, t1.z * sc, t1.w * sc);
            o4[2] = make_float4(t2.x * sc, t2.y * sc, t2.z * sc, t2.w * sc);
            o4[3] = make_float4(t3.x * sc, t3.y * sc, t3.z * sc, t3.w * sc);
        } else {
            const int b = row >> 3, o = row & 7;
            const float vv[16] = { t0.x, t0.y, t0.z, t0.w, t1.x, t1.y, t1.z, t1.w,
                                   t2.x, t2.y, t2.z, t2.w, t3.x, t3.y, t3.z, t3.w };
#pragma unroll
            for (int j = 0; j < 16; ++j)
                vT[(size_t)(o * 16 + j) * 256 + b] = f2bf(vv[j] * sc);
            // re-zero sp for the next iteration's atomics
            float4* z = (float4*)(sp + (size_t)row * 16);
            z[0] = make_float4(0.f, 0.f, 0.f, 0.f);
            z[1] = make_float4(0.f, 0.f, 0.f, 0.f);
            z[2] = make_float4(0.f, 0.f, 0.f, 0.f);
            z[3] = make_float4(0.f, 0.f, 0.f, 0.f);
        }
    }
}

// ---------------- agreement (MFMA) + bij + softmax + write cwt for next iter.
// Block = 8 i's. Phase 1: H[oc][(i,d)] = sum_b vT[oc][b]*xT[(i,d)][b].
// Phase 2: a[i,o] = (1/256) sum_{c,d} Wbf*H; softmax over o; cwt = c*Wbf.
template<bool FIRST>
__global__ __launch_bounds__(256, 2)
void a_gemm(const unsigned short* __restrict__ xT, const unsigned short* __restrict__ vT,
            const unsigned short* __restrict__ Wbf, float* __restrict__ bij,
            unsigned short* __restrict__ cwt)
{
    __shared__ __align__(16) char smraw[128 * 68 * 4];      // 34816 B (staging aliased)
    unsigned short* As = (unsigned short*)smraw;            // [128 oc][64 b]
    unsigned short* Bx = (unsigned short*)(smraw + 16384);  // [64 (i,d)][64 b]
    float* Hs = (float*)smraw;                              // [128][68]

    const int tid = threadIdx.x;
    const int i0  = blockIdx.x * 8;
    const int ln  = tid & 63, wv = tid >> 6;
    const int mr  = ln & 15, qd = ln >> 4;

    f32x4 acc[2][4];
#pragma unroll
    for (int a = 0; a < 2; ++a)
#pragma unroll
        for (int b = 0; b < 4; ++b) acc[a][b] = (f32x4){0.f, 0.f, 0.f, 0.f};

#pragma unroll 1
    for (int bc = 0; bc < 4; ++bc) {
        __syncthreads();
#pragma unroll
        for (int r = 0; r < 4; ++r) {          // As <- vT tile
            const int flat = r * 256 + tid;
            const int oc = flat >> 3, col = flat & 7;
            const short8 v = *(const short8*)(vT + (size_t)oc * 256 + bc * 64 + col * 8);
            *(short8*)&As[oc * 64 + ((col ^ (oc & 7)) * 8)] = v;
        }
#pragma unroll
        for (int r = 0; r < 2; ++r) {          // Bx <- xT rows i0*8..+63
            const int flat = r * 256 + tid;
            const int rw = flat >> 3, col = flat & 7;
            const short8 v = *(const short8*)(xT + (size_t)(i0 * 8 + rw) * 256 + bc * 64 + col * 8);
            *(short8*)&Bx[rw * 64 + ((col ^ (rw & 7)) * 8)] = v;
        }
        __syncthreads();
#pragma unroll
        for (int kk = 0; kk < 2; ++kk) {
            const int csw = ((kk * 4 + qd) ^ (mr & 7)) * 8;
#pragma unroll
            for (int nt = 0; nt < 4; ++nt) {
                const short8 b = *(const short8*)&Bx[(nt * 16 + mr) * 64 + csw];
#pragma unroll
                for (int mt = 0; mt < 2; ++mt) {
                    const short8 a = *(const short8*)&As[((wv * 2 + mt) * 16 + mr) * 64 + csw];
                    acc[mt][nt] = __builtin_amdgcn_mfma_f32_16x16x32_bf16(a, b, acc[mt][nt], 0, 0, 0);
                }
            }
        }
    }

    __syncthreads();
#pragma unroll
    for (int mt = 0; mt < 2; ++mt)
#pragma unroll
        for (int nt = 0; nt < 4; ++nt)
#pragma unroll
            for (int r = 0; r < 4; ++r)
                Hs[((wv * 2 + mt) * 16 + qd * 4 + r) * 68 + nt * 16 + mr] = acc[mt][nt][r];
    __syncthreads();

    // phase 2: tid = il*32 + oo*4 + ch
    const int ch = tid & 3, oo = (tid >> 2) & 7, il = tid >> 5;
    const int ival = i0 + il;
    const int gi = (ival < IC) ? ival : IC - 1;
    const unsigned short* Wt = Wbf + (size_t)(oo * 16 + ch * 4) * KP + (size_t)gi * 8;

    float wreg[4][8];
#pragma unroll
    for (int c = 0; c < 4; ++c) {
        union { short8 v; unsigned short h[8]; } uw;
        uw.v = *(const short8*)(Wt + (size_t)c * KP);
#pragma unroll
        for (int j = 0; j < 8; ++j) wreg[c][j] = bf2f(uw.h[j]);
    }
    float p = 0.0f;
#pragma unroll
    for (int c = 0; c < 4; ++c) {
        const float* hr = &Hs[(oo * 16 + ch * 4 + c) * 68 + il * 8];
        const float4 h0 = *(const float4*)hr;
        const float4 h1 = *(const float4*)(hr + 4);
        p = fmaf(wreg[c][0], h0.x, p); p = fmaf(wreg[c][1], h0.y, p);
        p = fmaf(wreg[c][2], h0.z, p); p = fmaf(wreg[c][3], h0.w, p);
        p = fmaf(wreg[c][4], h1.x, p); p = fmaf(wreg[c][5], h1.y, p);
        p = fmaf(wreg[c][6], h1.z, p); p = fmaf(wreg[c][7], h1.w, p);
    }
    p += __shfl_xor(p, 1); p += __shfl_xor(p, 2);   // combine ch quarters
    const float anew = p * (1.0f / 256.0f);
    float bv = anew;
    if (!FIRST) bv += bij[gi * 8 + oo];
    float mx = bv;                                   // softmax over oo (bits 2..4)
    mx = fmaxf(mx, __shfl_xor(mx, 4));
    mx = fmaxf(mx, __shfl_xor(mx, 8));
    mx = fmaxf(mx, __shfl_xor(mx, 16));
    const float e = expf(bv - mx);
    float ss = e;
    ss += __shfl_xor(ss, 4); ss += __shfl_xor(ss, 8); ss += __shfl_xor(ss, 16);
    float cv = e / ss;
    if (ival >= IC) cv = 0.0f;                       // keep cwt pad rows zero
    if (ch == 0 && ival < IC) bij[ival * 8 + oo] = bv;
#pragma unroll
    for (int c = 0; c < 4; ++c) {
        union { short8 v; unsigned short h[8]; } o;
#pragma unroll
        for (int j = 0; j < 8; ++j) o.h[j] = f2bf(cv * wreg[c][j]);
        *(short8*)(cwt + (size_t)(oo * 16 + ch * 4 + c) * KP + (size_t)ival * 8) = o.v;
    }
}

extern "C" void kernel_launch(void* const* d_in, const int* in_sizes, int n_in,
                              void* d_out, int out_size, void* d_ws, size_t ws_size,
                              hipStream_t stream)
{
    const float* x = (const float*)d_in[0];   // [256, 2401, 8]
    const float* W = (const float*)d_in[1];   // [2401, 8, 16, 8]
    float* out = (float*)d_out;               // [256, 8, 16]

    char* p = (char*)d_ws;
    float*          sp   = (float*)p;          p += (size_t)BSZ * OCC * 4;        // 128 KB
    unsigned short* xT   = (unsigned short*)p; p += (size_t)KP * 256 * 2;         // 9.86 MB
    unsigned short* xB   = (unsigned short*)p; p += (size_t)256 * KP * 2;         // 9.86 MB
    unsigned short* Wbf  = (unsigned short*)p; p += (size_t)128 * KP * 2;         // 4.93 MB
    unsigned short* cwt  = (unsigned short*)p; p += (size_t)128 * KP * 2;         // 4.93 MB
    unsigned short* vT   = (unsigned short*)p; p += (size_t)128 * 256 * 2;        // 64 KB
    float*          bij  = (float*)p;          p += (size_t)IC * 8 * 4;           // 77 KB
    unsigned int*   ctr  = (unsigned int*)p;                                      // 12 B

    const dim3 sgrid(4, NI);

    prep_kernel<<<1505, 256, 0, stream>>>(x, W, xT, xB, Wbf, cwt, sp, ctr);

    sv_kernel<<<sgrid, 256, 0, stream>>>(xB, cwt, sp, ctr + 0, vT, out, 0);
    a_gemm<true><<<KTILES, 256, 0, stream>>>(xT, vT, Wbf, bij, cwt);

    sv_kernel<<<sgrid, 256, 0, stream>>>(xB, cwt, sp, ctr + 1, vT, out, 0);
    a_gemm<false><<<KTILES, 256, 0, stream>>>(xT, vT, Wbf, bij, cwt);

    sv_kernel<<<sgrid, 256, 0, stream>>>(xB, cwt, sp, ctr + 2, vT, out, 1);
}

// Round 9
// 153.310 us; speedup vs baseline: 1.3797x; 1.3797x over previous
//
#include <hip/hip_runtime.h>
#include <math.h>

#define IC     2401
#define BSZ    256
#define OC     8
#define CS     16
#define OCC    128     // OC*CS
#define XROW   19208   // x row length (floats) = IC*8
#define KP     19264   // padded K (=301*64), pad zeroed
#define KTILES 301
#define NI     64      // split-K slices for s_gemm

typedef __attribute__((ext_vector_type(8))) short short8;
typedef __attribute__((ext_vector_type(4))) float f32x4;

__device__ __forceinline__ unsigned short f2bf(float f) {
    union { float f; unsigned u; } v; v.f = f;
    const unsigned r = v.u + 0x7FFF + ((v.u >> 16) & 1);   // RNE
    return (unsigned short)(r >> 16);
}
__device__ __forceinline__ float bf2f(unsigned short h) {
    union { unsigned u; float f; } v; v.u = ((unsigned)h) << 16;
    return v.f;
}

// ---------------- prep: xT[k][b] bf16, xB[b][k] bf16, Wbf/cwt0 [oc][k] bf16 ----------
__global__ __launch_bounds__(256)
void prep_kernel(const float* __restrict__ x, const float* __restrict__ W,
                 unsigned short* __restrict__ xT, unsigned short* __restrict__ xB,
                 unsigned short* __restrict__ Wbf, unsigned short* __restrict__ cwt)
{
    const int tid = threadIdx.x;
    if (blockIdx.x < 1204) {
        __shared__ float Ts[64 * 65];
        const int bg = blockIdx.x & 3;       // b-group of 64
        const int kt = blockIdx.x >> 2;      // k-tile 0..300
#pragma unroll
        for (int r = 0; r < 4; ++r) {
            const int flat = r * 256 + tid;  // 1024 float4s
            const int b = flat >> 4, cq = flat & 15;
            const int col = kt * 64 + cq * 4;
            float4 v = make_float4(0.f, 0.f, 0.f, 0.f);
            if (col < XROW) v = *(const float4*)(x + (size_t)(bg * 64 + b) * XROW + col);
            *(float4*)&Ts[b * 65 + cq * 4] = v;
        }
        __syncthreads();
        // xT[k][b]
#pragma unroll
        for (int r = 0; r < 2; ++r) {
            const int flat = r * 256 + tid;
            const int rl = flat >> 3, bq = flat & 7;
            union { short8 v; unsigned short h[8]; } o;
#pragma unroll
            for (int j = 0; j < 8; ++j) o.h[j] = f2bf(Ts[(bq * 8 + j) * 65 + rl]);
            *(short8*)(xT + (size_t)(kt * 64 + rl) * 256 + bg * 64 + bq * 8) = o.v;
        }
        // xB[b][k]
#pragma unroll
        for (int r = 0; r < 2; ++r) {
            const int flat = r * 256 + tid;
            const int b = flat >> 3, g = flat & 7;
            union { short8 v; unsigned short h[8]; } o;
#pragma unroll
            for (int j = 0; j < 8; ++j) o.h[j] = f2bf(Ts[b * 65 + g * 8 + j]);
            *(short8*)(xB + (size_t)(bg * 64 + b) * KP + (size_t)kt * 64 + g * 8) = o.v;
        }
    } else {
        __shared__ float Ws[8 * 1032];
        const int i0 = (blockIdx.x - 1204) * 8;
#pragma unroll
        for (int r = 0; r < 8; ++r) {
            const int flat = r * 256 + tid;
            const int g = flat >> 8, rem = flat & 255;
            int gi = i0 + g; if (gi > 2400) gi = 2400;
            *(float4*)&Ws[g * 1032 + rem * 4] = *(const float4*)(W + (size_t)gi * 1024 + rem * 4);
        }
        __syncthreads();
#pragma unroll
        for (int r = 0; r < 4; ++r) {
            const int flat = r * 256 + tid;
            const int oc = flat >> 3, g = flat & 7;
            const int gi = i0 + g;
            union { short8 v; unsigned short h[8]; } w, c;
            if (gi <= 2400) {
                const float* wp = &Ws[g * 1032 + oc * 8];
#pragma unroll
                for (int j = 0; j < 8; ++j) { w.h[j] = f2bf(wp[j]); c.h[j] = f2bf(0.125f * wp[j]); }
            } else {
#pragma unroll
                for (int j = 0; j < 8; ++j) { w.h[j] = 0; c.h[j] = 0; }
            }
            *(short8*)(Wbf + (size_t)oc * KP + (size_t)gi * 8) = w.v;
            *(short8*)(cwt + (size_t)oc * KP + (size_t)gi * 8) = c.v;
        }
    }
}

// ---------------- s partials, barrier-free: MFMA fragments loaded STRAIGHT from
// global (xB / cwt rows are exactly the A/B lane layouts: lane(mr,qd) -> 16B at
// row*KP + k + qd*8). No LDS, no __syncthreads in the K-loop -> deep load pipelining.
// grid (4 bg, NI); block = 4 waves; wave w: b-rows bg*64+w*16..+15, all 128 oc.
__global__ __launch_bounds__(256)
void s_gemm(const unsigned short* __restrict__ xB, const unsigned short* __restrict__ cwt,
            float* __restrict__ spart)
{
    const int tid = threadIdx.x;
    const int bg  = blockIdx.x, iy = blockIdx.y;
    const int w   = tid >> 6;
    const int ln  = tid & 63;
    const int mr  = ln & 15, qd = ln >> 4;
    const int m0  = bg * 64 + w * 16;

    const unsigned short* ap = xB + (size_t)(m0 + mr) * KP + qd * 8;
    const unsigned short* bp = cwt + (size_t)mr * KP + qd * 8;

    f32x4 acc[8];
#pragma unroll
    for (int n = 0; n < 8; ++n) acc[n] = (f32x4){0.f, 0.f, 0.f, 0.f};

#pragma unroll 1
    for (int kt = iy; kt < KTILES; kt += NI) {
        const int kbase = kt * 64;
#pragma unroll
        for (int kk = 0; kk < 2; ++kk) {
            const int k = kbase + kk * 32;
            const short8 a = *(const short8*)(ap + k);
#pragma unroll
            for (int nt = 0; nt < 8; ++nt) {
                const short8 b = *(const short8*)(bp + (size_t)(nt * 16) * KP + k);
                acc[nt] = __builtin_amdgcn_mfma_f32_16x16x32_bf16(a, b, acc[nt], 0, 0, 0);
            }
        }
    }

    float* op = spart + (size_t)iy * (BSZ * OCC);
#pragma unroll
    for (int nt = 0; nt < 8; ++nt)
#pragma unroll
        for (int r = 0; r < 4; ++r)
            op[(size_t)(m0 + qd * 4 + r) * OCC + nt * 16 + mr] = acc[nt][r];
}

// ---------------- reduce NI split-K partials + squash, full-chip spread.
// grid 256 blocks x 256 thr; block = 8 (b,o)-rows; 2-way k split per element.
__global__ __launch_bounds__(256)
void squash_kernel(const float* __restrict__ spart, float* __restrict__ vout,
                   unsigned short* __restrict__ vT, int writeT)
{
    __shared__ float red[256];
    const int tid = threadIdx.x;
    const int r0  = blockIdx.x * 8;          // first of 8 rows (row = b*8+o)
    const int idx = tid & 127;               // element within 8x16 chunk
    const int k0  = tid >> 7;                // k parity

    const float* base = spart + (size_t)r0 * 16 + idx;
    float acc = 0.0f;
#pragma unroll 8
    for (int k = k0; k < NI; k += 2) acc += base[(size_t)k * (BSZ * OCC)];
    red[tid] = acc;
    __syncthreads();

    if (tid < 128) {
        const float s = red[tid] + red[tid + 128];
        float ms = s * s;
        ms += __shfl_xor(ms, 1); ms += __shfl_xor(ms, 2);
        ms += __shfl_xor(ms, 4); ms += __shfl_xor(ms, 8);
        const float scale = sqrtf(ms) / (1.0f + ms);   // == mag_sq/(1+mag_sq)/mag
        const float outv = s * scale;
        const int row = r0 + (tid >> 4);     // = b*8 + o
        const int j   = tid & 15;
        if (writeT) {
            vT[(size_t)((row & 7) * 16 + j) * 256 + (row >> 3)] = f2bf(outv);
        } else {
            vout[(size_t)row * 16 + j] = outv;
        }
    }
}

// ---------------- agreement (MFMA) + bij + softmax + write cwt for next iter.
// Block = 8 i's. Phase 1: H[oc][(i,d)] = sum_b vT[oc][b]*xT[(i,d)][b].
// Phase 2: a[i,o] = (1/256) sum_{c,d} Wbf*H; softmax over o; cwt = c*Wbf.
template<bool FIRST>
__global__ __launch_bounds__(256, 2)
void a_gemm(const unsigned short* __restrict__ xT, const unsigned short* __restrict__ vT,
            const unsigned short* __restrict__ Wbf, float* __restrict__ bij,
            unsigned short* __restrict__ cwt)
{
    __shared__ __align__(16) char smraw[128 * 68 * 4];      // 34816 B (staging aliased)
    unsigned short* As = (unsigned short*)smraw;            // [128 oc][64 b]
    unsigned short* Bx = (unsigned short*)(smraw + 16384);  // [64 (i,d)][64 b]
    float* Hs = (float*)smraw;                              // [128][68]

    const int tid = threadIdx.x;
    const int i0  = blockIdx.x * 8;
    const int ln  = tid & 63, wv = tid >> 6;
    const int mr  = ln & 15, qd = ln >> 4;

    f32x4 acc[2][4];
#pragma unroll
    for (int a = 0; a < 2; ++a)
#pragma unroll
        for (int b = 0; b < 4; ++b) acc[a][b] = (f32x4){0.f, 0.f, 0.f, 0.f};

#pragma unroll 1
    for (int bc = 0; bc < 4; ++bc) {
        __syncthreads();
#pragma unroll
        for (int r = 0; r < 4; ++r) {          // As <- vT tile
            const int flat = r * 256 + tid;
            const int oc = flat >> 3, col = flat & 7;
            const short8 v = *(const short8*)(vT + (size_t)oc * 256 + bc * 64 + col * 8);
            *(short8*)&As[oc * 64 + ((col ^ (oc & 7)) * 8)] = v;
        }
#pragma unroll
        for (int r = 0; r < 2; ++r) {          // Bx <- xT rows i0*8..+63
            const int flat = r * 256 + tid;
            const int rw = flat >> 3, col = flat & 7;
            const short8 v = *(const short8*)(xT + (size_t)(i0 * 8 + rw) * 256 + bc * 64 + col * 8);
            *(short8*)&Bx[rw * 64 + ((col ^ (rw & 7)) * 8)] = v;
        }
        __syncthreads();
#pragma unroll
        for (int kk = 0; kk < 2; ++kk) {
            const int csw = ((kk * 4 + qd) ^ (mr & 7)) * 8;
#pragma unroll
            for (int nt = 0; nt < 4; ++nt) {
                const short8 b = *(const short8*)&Bx[(nt * 16 + mr) * 64 + csw];
#pragma unroll
                for (int mt = 0; mt < 2; ++mt) {
                    const short8 a = *(const short8*)&As[((wv * 2 + mt) * 16 + mr) * 64 + csw];
                    acc[mt][nt] = __builtin_amdgcn_mfma_f32_16x16x32_bf16(a, b, acc[mt][nt], 0, 0, 0);
                }
            }
        }
    }

    __syncthreads();
#pragma unroll
    for (int mt = 0; mt < 2; ++mt)
#pragma unroll
        for (int nt = 0; nt < 4; ++nt)
#pragma unroll
            for (int r = 0; r < 4; ++r)
                Hs[((wv * 2 + mt) * 16 + qd * 4 + r) * 68 + nt * 16 + mr] = acc[mt][nt][r];
    __syncthreads();

    // phase 2: tid = il*32 + oo*4 + ch
    const int ch = tid & 3, oo = (tid >> 2) & 7, il = tid >> 5;
    const int ival = i0 + il;
    const int gi = (ival < IC) ? ival : IC - 1;
    const unsigned short* Wt = Wbf + (size_t)(oo * 16 + ch * 4) * KP + (size_t)gi * 8;

    float wreg[4][8];
#pragma unroll
    for (int c = 0; c < 4; ++c) {
        union { short8 v; unsigned short h[8]; } uw;
        uw.v = *(const short8*)(Wt + (size_t)c * KP);
#pragma unroll
        for (int j = 0; j < 8; ++j) wreg[c][j] = bf2f(uw.h[j]);
    }
    float p = 0.0f;
#pragma unroll
    for (int c = 0; c < 4; ++c) {
        const float* hr = &Hs[(oo * 16 + ch * 4 + c) * 68 + il * 8];
        const float4 h0 = *(const float4*)hr;
        const float4 h1 = *(const float4*)(hr + 4);
        p = fmaf(wreg[c][0], h0.x, p); p = fmaf(wreg[c][1], h0.y, p);
        p = fmaf(wreg[c][2], h0.z, p); p = fmaf(wreg[c][3], h0.w, p);
        p = fmaf(wreg[c][4], h1.x, p); p = fmaf(wreg[c][5], h1.y, p);
        p = fmaf(wreg[c][6], h1.z, p); p = fmaf(wreg[c][7], h1.w, p);
    }
    p += __shfl_xor(p, 1); p += __shfl_xor(p, 2);   // combine ch quarters
    const float anew = p * (1.0f / 256.0f);
    float bv = anew;
    if (!FIRST) bv += bij[gi * 8 + oo];
    float mx = bv;                                   // softmax over oo (bits 2..4)
    mx = fmaxf(mx, __shfl_xor(mx, 4));
    mx = fmaxf(mx, __shfl_xor(mx, 8));
    mx = fmaxf(mx, __shfl_xor(mx, 16));
    const float e = expf(bv - mx);
    float ss = e;
    ss += __shfl_xor(ss, 4); ss += __shfl_xor(ss, 8); ss += __shfl_xor(ss, 16);
    float cv = e / ss;
    if (ival >= IC) cv = 0.0f;                       // keep cwt pad rows zero
    if (ch == 0 && ival < IC) bij[ival * 8 + oo] = bv;
#pragma unroll
    for (int c = 0; c < 4; ++c) {
        union { short8 v; unsigned short h[8]; } o;
#pragma unroll
        for (int j = 0; j < 8; ++j) o.h[j] = f2bf(cv * wreg[c][j]);
        *(short8*)(cwt + (size_t)(oo * 16 + ch * 4 + c) * KP + (size_t)ival * 8) = o.v;
    }
}

extern "C" void kernel_launch(void* const* d_in, const int* in_sizes, int n_in,
                              void* d_out, int out_size, void* d_ws, size_t ws_size,
                              hipStream_t stream)
{
    const float* x = (const float*)d_in[0];   // [256, 2401, 8]
    const float* W = (const float*)d_in[1];   // [2401, 8, 16, 8]
    float* out = (float*)d_out;               // [256, 8, 16]

    char* p = (char*)d_ws;
    float*          spart = (float*)p;          p += (size_t)NI * BSZ * OCC * 4;   // 8.39 MB
    unsigned short* xT    = (unsigned short*)p; p += (size_t)KP * 256 * 2;         // 9.86 MB
    unsigned short* xB    = (unsigned short*)p; p += (size_t)256 * KP * 2;         // 9.86 MB
    unsigned short* Wbf   = (unsigned short*)p; p += (size_t)128 * KP * 2;         // 4.93 MB
    unsigned short* cwt   = (unsigned short*)p; p += (size_t)128 * KP * 2;         // 4.93 MB
    unsigned short* vT    = (unsigned short*)p; p += (size_t)128 * 256 * 2;        // 64 KB
    float*          bij   = (float*)p;                                            // 77 KB

    const dim3 sgrid(4, NI);

    prep_kernel<<<1505, 256, 0, stream>>>(x, W, xT, xB, Wbf, cwt);

    // iter 0
    s_gemm<<<sgrid, 256, 0, stream>>>(xB, cwt, spart);
    squash_kernel<<<256, 256, 0, stream>>>(spart, nullptr, vT, 1);
    a_gemm<true><<<KTILES, 256, 0, stream>>>(xT, vT, Wbf, bij, cwt);
    // iter 1
    s_gemm<<<sgrid, 256, 0, stream>>>(xB, cwt, spart);
    squash_kernel<<<256, 256, 0, stream>>>(spart, nullptr, vT, 1);
    a_gemm<false><<<KTILES, 256, 0, stream>>>(xT, vT, Wbf, bij, cwt);
    // iter 2 (final)
    s_gemm<<<sgrid, 256, 0, stream>>>(xB, cwt, spart);
    squash_kernel<<<256, 256, 0, stream>>>(spart, out, vT, 0);
}